// Round 1
// baseline (429.579 us; speedup 1.0000x reference)
//
#include <hip/hip_runtime.h>

// ---------------------------------------------------------------------------
// MultiHeadAttention: B=8, S=1024, D=1024, H=16, dh=64
// outputs: out [8,1024,1024] f32, qk [8,16,1024,1024] f32 (concat in d_out)
// ---------------------------------------------------------------------------

typedef unsigned short u16;
typedef unsigned int   u32;
typedef __attribute__((ext_vector_type(8))) __bf16 bf16x8;
typedef __attribute__((ext_vector_type(4))) float  f32x4;

__device__ __forceinline__ u16 f2bf(float f) {
  u32 u = __float_as_uint(f);
  u += 0x7FFFu + ((u >> 16) & 1u);   // round-to-nearest-even
  return (u16)(u >> 16);
}
__device__ __forceinline__ float bf2f(u16 v) {
  return __uint_as_float(((u32)v) << 16);
}
__device__ __forceinline__ f32x4 mfma16(bf16x8 a, bf16x8 b, f32x4 c) {
  return __builtin_amdgcn_mfma_f32_16x16x32_bf16(a, b, c, 0, 0, 0);
}
typedef __attribute__((address_space(3))) u32 lds_u32;
typedef const __attribute__((address_space(1))) u32 glb_u32;
__device__ __forceinline__ void gld_lds16(u16* lds, const u16* g) {
  // LDS dest = wave-uniform base + lane*16 (linear); global src per-lane.
  __builtin_amdgcn_global_load_lds((glb_u32*)g, (lds_u32*)lds, 16, 0, 0);
}
__device__ __forceinline__ bf16x8 ld_bf8(const u16* p) {
  return *(const bf16x8*)p;
}

// ---------------------------------------------------------------------------
// f32 -> bf16 conversion (vectorized, 8 elems/thread)
// ---------------------------------------------------------------------------
__global__ __launch_bounds__(256) void cvt_f32_bf16(
    const float* __restrict__ src, u16* __restrict__ dst, int n) {
  int i = (blockIdx.x * 256 + threadIdx.x) * 8;
  if (i >= n) return;
  const float4* s = (const float4*)(src + i);
  float4 a = s[0], b = s[1];
  u16 r[8];
  r[0] = f2bf(a.x); r[1] = f2bf(a.y); r[2] = f2bf(a.z); r[3] = f2bf(a.w);
  r[4] = f2bf(b.x); r[5] = f2bf(b.y); r[6] = f2bf(b.z); r[7] = f2bf(b.w);
  *(uint4*)(dst + i) = *(const uint4*)r;
}

// ---------------------------------------------------------------------------
// Projection GEMM: C[8192, 3072] = xb @ [Wq;Wk;Wv]^T  (K=1024, BK=32, 128x128)
//   region 0 -> Qb = (C+bq)*scale   [m][n] bf16
//   region 1 -> Kb = C*scale        [m][n] bf16
//   region 2 -> Vt = C+bv           transposed [b][h][d][s] bf16
// ---------------------------------------------------------------------------
__global__ __launch_bounds__(256) void proj_gemm(
    const u16* __restrict__ xb,
    const u16* __restrict__ Wqb, const u16* __restrict__ Wkb,
    const u16* __restrict__ Wvb,
    const float* __restrict__ bq, const float* __restrict__ bv,
    u16* __restrict__ Qb, u16* __restrict__ Kb, u16* __restrict__ Vt) {
  __shared__ u16 As[128][32];
  __shared__ u16 Bs[128][32];
  const int tid  = threadIdx.x;
  const int lane = tid & 63;
  const int wid  = tid >> 6;
  const int c15  = lane & 15, c4 = lane >> 4;
  const int m0   = blockIdx.x * 128;
  const int nv0  = blockIdx.y * 128;          // virtual col in [0,3072)
  const int region = nv0 >> 10;               // 0=q 1=k 2=v (1024-aligned)
  const int nl0  = nv0 & 1023;
  const u16* Wsrc = (region == 0) ? Wqb : (region == 1) ? Wkb : Wvb;
  const int wrow = wid >> 1, wcol = wid & 1;
  const int srow = lane >> 2, scol = (lane & 3) * 8;

  f32x4 acc[4][4] = {};

  for (int k0 = 0; k0 < 1024; k0 += 32) {
#pragma unroll
    for (int j = 0; j < 2; ++j) {
      const int r = 64 * j + 16 * wid;
      gld_lds16(&As[r][0], xb   + (m0  + r + srow) * 1024 + k0 + scol);
      gld_lds16(&Bs[r][0], Wsrc + (nl0 + r + srow) * 1024 + k0 + scol);
    }
    __syncthreads();
    bf16x8 af[4], bfr[4];
#pragma unroll
    for (int a = 0; a < 4; ++a) af[a]  = ld_bf8(&As[64 * wrow + 16 * a + c15][8 * c4]);
#pragma unroll
    for (int b = 0; b < 4; ++b) bfr[b] = ld_bf8(&Bs[64 * wcol + 16 * b + c15][8 * c4]);
#pragma unroll
    for (int a = 0; a < 4; ++a)
#pragma unroll
      for (int b = 0; b < 4; ++b)
        acc[a][b] = mfma16(af[a], bfr[b], acc[a][b]);
    __syncthreads();
  }

  const float kSc = 0.35355339059327373f;  // 64^-0.25
#pragma unroll
  for (int a = 0; a < 4; ++a) {
    const int mg = m0 + 64 * wrow + 16 * a + 4 * c4;
#pragma unroll
    for (int b = 0; b < 4; ++b) {
      const int nl = 64 * wcol + 16 * b + c15;
      const int nv = nv0 + nl;
      if (region == 0) {
        const float bias = bq[nv];
#pragma unroll
        for (int j = 0; j < 4; ++j)
          Qb[(mg + j) * 1024 + nv] = f2bf((acc[a][b][j] + bias) * kSc);
      } else if (region == 1) {
        const int n = nv - 1024;
#pragma unroll
        for (int j = 0; j < 4; ++j)
          Kb[(mg + j) * 1024 + n] = f2bf(acc[a][b][j] * kSc);
      } else {
        const int n = nv - 2048;             // h*64+d
        const float bias = bv[n];
        const int bb = mg >> 10;             // batch (same for all j)
        u16* vp = Vt + ((bb * 16 + (n >> 6)) * 64 + (n & 63)) * 1024;
#pragma unroll
        for (int j = 0; j < 4; ++j)
          vp[(mg + j) & 1023] = f2bf(acc[a][b][j] + bias);
      }
    }
  }
}

// ---------------------------------------------------------------------------
// Attention: one block = (b, h, 32-row q-tile). 4 waves.
//  phase 1: S = Q K^T + mask, write qk (f32), park bf16 S in LDS
//  phase 2: exact softmax from LDS (row max/sum), P back to LDS (unnormalized)
//  phase 3: O = P V / l ; V fragments loaded direct from global Vt (L2-hot)
// ---------------------------------------------------------------------------
__global__ __launch_bounds__(256) void attn_kernel(
    const u16* __restrict__ Qb, const u16* __restrict__ Kb,
    const u16* __restrict__ Vt, const float* __restrict__ mask,
    float* __restrict__ qk, u16* __restrict__ WV) {
  __shared__ u16 S_lds[32][1032];            // 66 KB (pad 8 -> 2-way-free banks)
  __shared__ float inv_l[32];
  const int tid  = threadIdx.x;
  const int lane = tid & 63;
  const int w    = tid >> 6;
  const int c15  = lane & 15, c4 = lane >> 4;
  const int qt = blockIdx.x, h = blockIdx.y, b = blockIdx.z;
  const int q0  = qt * 32;
  const int bs0 = b * 1024;

  // Q fragments (rows q0..q0+31, d 0..63), reused across all k
  bf16x8 qf[2][2];
#pragma unroll
  for (int a = 0; a < 2; ++a)
#pragma unroll
    for (int kk = 0; kk < 2; ++kk)
      qf[a][kk] = ld_bf8(&Qb[(bs0 + q0 + 16 * a + c15) * 1024 + h * 64 + 32 * kk + 8 * c4]);

  // ---- phase 1: QK^T; wave w covers s_k in [256w, 256w+256)
  for (int c = 0; c < 16; ++c) {
    const int sk0 = 256 * w + 16 * c;
    bf16x8 kf[2];
#pragma unroll
    for (int kk = 0; kk < 2; ++kk)
      kf[kk] = ld_bf8(&Kb[(bs0 + sk0 + c15) * 1024 + h * 64 + 32 * kk + 8 * c4]);
    f32x4 acc[2] = {};
#pragma unroll
    for (int kk = 0; kk < 2; ++kk) {
      acc[0] = mfma16(qf[0][kk], kf[kk], acc[0]);
      acc[1] = mfma16(qf[1][kk], kf[kk], acc[1]);
    }
    const int col = sk0 + c15;
#pragma unroll
    for (int a = 0; a < 2; ++a) {
      const int rl = 16 * a + 4 * c4;
#pragma unroll
      for (int j = 0; j < 4; ++j) {
        const float v = acc[a][j] + mask[(q0 + rl + j) * 1024 + col];
        qk[((b * 16 + h) * 1024 + q0 + rl + j) * 1024 + col] = v;
        S_lds[rl + j][col] = f2bf(v);
      }
    }
  }
  __syncthreads();

  // ---- phase 2: softmax (8 threads per row)
  {
    const int row = tid >> 3, sub = tid & 7;
    float m = -1e30f;
#pragma unroll 4
    for (int i = 0; i < 16; ++i) {
      bf16x8 v = ld_bf8(&S_lds[row][(sub + 8 * i) * 8]);
      const u16* vu = (const u16*)&v;
#pragma unroll
      for (int e = 0; e < 8; ++e) m = fmaxf(m, bf2f(vu[e]));
    }
    m = fmaxf(m, __shfl_xor(m, 1, 8));
    m = fmaxf(m, __shfl_xor(m, 2, 8));
    m = fmaxf(m, __shfl_xor(m, 4, 8));
    float s = 0.f;
#pragma unroll 4
    for (int i = 0; i < 16; ++i) {
      bf16x8 v = ld_bf8(&S_lds[row][(sub + 8 * i) * 8]);
      const u16* vu = (const u16*)&v;
      u16 p[8];
#pragma unroll
      for (int e = 0; e < 8; ++e) {
        const float pe = __expf(bf2f(vu[e]) - m);
        s += pe;
        p[e] = f2bf(pe);
      }
      *(uint4*)&S_lds[row][(sub + 8 * i) * 8] = *(const uint4*)p;
    }
    s += __shfl_xor(s, 1, 8);
    s += __shfl_xor(s, 2, 8);
    s += __shfl_xor(s, 4, 8);
    if (sub == 0) inv_l[row] = 1.0f / s;
  }
  __syncthreads();

  // ---- phase 3: PV; wave w computes output cols d in [16w, 16w+16)
  f32x4 oacc[2] = {};
  const u16* vbase = Vt + ((b * 16 + h) * 64 + 16 * w + c15) * 1024;
  for (int t = 0; t < 32; ++t) {
    bf16x8 pa0 = ld_bf8(&S_lds[c15][32 * t + 8 * c4]);
    bf16x8 pa1 = ld_bf8(&S_lds[16 + c15][32 * t + 8 * c4]);
    bf16x8 vb  = ld_bf8(vbase + 32 * t + 8 * c4);
    oacc[0] = mfma16(pa0, vb, oacc[0]);
    oacc[1] = mfma16(pa1, vb, oacc[1]);
  }
  const int d = 16 * w + c15;
#pragma unroll
  for (int a = 0; a < 2; ++a) {
    const int rl = 16 * a + 4 * c4;
#pragma unroll
    for (int j = 0; j < 4; ++j) {
      const float v = oacc[a][j] * inv_l[rl + j];
      WV[(bs0 + q0 + rl + j) * 1024 + h * 64 + d] = f2bf(v);
    }
  }
}

// ---------------------------------------------------------------------------
// Output GEMM: out[8192,1024] = WV @ Wo^T + bo  (f32 out)
// ---------------------------------------------------------------------------
__global__ __launch_bounds__(256) void out_gemm(
    const u16* __restrict__ Ab, const u16* __restrict__ Wb,
    const float* __restrict__ bias, float* __restrict__ outp) {
  __shared__ u16 As[128][32];
  __shared__ u16 Bs[128][32];
  const int tid  = threadIdx.x;
  const int lane = tid & 63;
  const int wid  = tid >> 6;
  const int c15  = lane & 15, c4 = lane >> 4;
  const int m0   = blockIdx.x * 128;
  const int n0   = blockIdx.y * 128;
  const int wrow = wid >> 1, wcol = wid & 1;
  const int srow = lane >> 2, scol = (lane & 3) * 8;

  f32x4 acc[4][4] = {};

  for (int k0 = 0; k0 < 1024; k0 += 32) {
#pragma unroll
    for (int j = 0; j < 2; ++j) {
      const int r = 64 * j + 16 * wid;
      gld_lds16(&As[r][0], Ab + (m0 + r + srow) * 1024 + k0 + scol);
      gld_lds16(&Bs[r][0], Wb + (n0 + r + srow) * 1024 + k0 + scol);
    }
    __syncthreads();
    bf16x8 af[4], bfr[4];
#pragma unroll
    for (int a = 0; a < 4; ++a) af[a]  = ld_bf8(&As[64 * wrow + 16 * a + c15][8 * c4]);
#pragma unroll
    for (int b = 0; b < 4; ++b) bfr[b] = ld_bf8(&Bs[64 * wcol + 16 * b + c15][8 * c4]);
#pragma unroll
    for (int a = 0; a < 4; ++a)
#pragma unroll
      for (int b = 0; b < 4; ++b)
        acc[a][b] = mfma16(af[a], bfr[b], acc[a][b]);
    __syncthreads();
  }

#pragma unroll
  for (int a = 0; a < 4; ++a) {
    const int mg = m0 + 64 * wrow + 16 * a + 4 * c4;
#pragma unroll
    for (int b = 0; b < 4; ++b) {
      const int ng = n0 + 64 * wcol + 16 * b + c15;
      const float bi = bias[ng];
#pragma unroll
      for (int j = 0; j < 4; ++j)
        outp[(mg + j) * 1024 + ng] = acc[a][b][j] + bi;
    }
  }
}

// ---------------------------------------------------------------------------
extern "C" void kernel_launch(void* const* d_in, const int* in_sizes, int n_in,
                              void* d_out, int out_size, void* d_ws, size_t ws_size,
                              hipStream_t stream) {
  const float* x    = (const float*)d_in[0];
  const float* mask = (const float*)d_in[1];
  const float* Wq   = (const float*)d_in[2];
  const float* bq   = (const float*)d_in[3];
  const float* Wk   = (const float*)d_in[4];
  const float* Wv   = (const float*)d_in[5];
  const float* bv   = (const float*)d_in[6];
  const float* Wo   = (const float*)d_in[7];
  const float* bo   = (const float*)d_in[8];

  float* outp = (float*)d_out;
  float* qk   = outp + 8 * 1024 * 1024;      // second output

  // workspace (bf16 elements): ~88 MB total
  u16* ws  = (u16*)d_ws;
  u16* xb  = ws;                    // 8388608
  u16* Wqb = xb  + 8388608;         // 1048576
  u16* Wkb = Wqb + 1048576;
  u16* Wvb = Wkb + 1048576;
  u16* Wob = Wvb + 1048576;
  u16* Qb  = Wob + 1048576;         // 8388608 (scaled)
  u16* Kb  = Qb  + 8388608;         // 8388608 (scaled)
  u16* Vt  = Kb  + 8388608;         // 8388608 ([b][h][d][s])
  u16* WV  = Vt  + 8388608;         // 8388608

  cvt_f32_bf16<<<4096, 256, 0, stream>>>(x,  xb,  8388608);
  cvt_f32_bf16<<<512,  256, 0, stream>>>(Wq, Wqb, 1048576);
  cvt_f32_bf16<<<512,  256, 0, stream>>>(Wk, Wkb, 1048576);
  cvt_f32_bf16<<<512,  256, 0, stream>>>(Wv, Wvb, 1048576);
  cvt_f32_bf16<<<512,  256, 0, stream>>>(Wo, Wob, 1048576);

  proj_gemm<<<dim3(64, 24), 256, 0, stream>>>(xb, Wqb, Wkb, Wvb, bq, bv, Qb, Kb, Vt);
  attn_kernel<<<dim3(32, 16, 8), 256, 0, stream>>>(Qb, Kb, Vt, mask, qk, WV);
  out_gemm<<<dim3(64, 8), 256, 0, stream>>>(WV, Wob, bo, outp);
}

// Round 2
// 378.514 us; speedup vs baseline: 1.1349x; 1.1349x over previous
//
#include <hip/hip_runtime.h>

// ---------------------------------------------------------------------------
// MultiHeadAttention: B=8, S=1024, D=1024, H=16, dh=64
// outputs: out [8,1024,1024] f32, qk [8,16,1024,1024] f32 (concat in d_out)
// ---------------------------------------------------------------------------

typedef unsigned short u16;
typedef unsigned int   u32;
typedef __attribute__((ext_vector_type(8)))  __bf16 bf16x8;
typedef __attribute__((ext_vector_type(4)))  float  f32x4;
typedef __attribute__((ext_vector_type(16))) float  f32x16;

__device__ __forceinline__ u16 f2bf(float f) {
  u32 u = __float_as_uint(f);
  u += 0x7FFFu + ((u >> 16) & 1u);   // round-to-nearest-even
  return (u16)(u >> 16);
}
__device__ __forceinline__ float bf2f(u16 v) {
  return __uint_as_float(((u32)v) << 16);
}
__device__ __forceinline__ f32x4 mfma16(bf16x8 a, bf16x8 b, f32x4 c) {
  return __builtin_amdgcn_mfma_f32_16x16x32_bf16(a, b, c, 0, 0, 0);
}
__device__ __forceinline__ f32x16 mfma32(bf16x8 a, bf16x8 b, f32x16 c) {
  return __builtin_amdgcn_mfma_f32_32x32x16_bf16(a, b, c, 0, 0, 0);
}
typedef __attribute__((address_space(3))) u32 lds_u32;
typedef const __attribute__((address_space(1))) u32 glb_u32;
__device__ __forceinline__ void gld_lds16(u16* lds, const u16* g) {
  __builtin_amdgcn_global_load_lds((glb_u32*)g, (lds_u32*)lds, 16, 0, 0);
}
__device__ __forceinline__ bf16x8 ld_bf8(const u16* p) {
  return *(const bf16x8*)p;
}

// ---------------------------------------------------------------------------
// f32 -> bf16 conversion (vectorized, 8 elems/thread)
// ---------------------------------------------------------------------------
__global__ __launch_bounds__(256) void cvt_f32_bf16(
    const float* __restrict__ src, u16* __restrict__ dst, int n) {
  int i = (blockIdx.x * 256 + threadIdx.x) * 8;
  if (i >= n) return;
  const float4* s = (const float4*)(src + i);
  float4 a = s[0], b = s[1];
  u16 r[8];
  r[0] = f2bf(a.x); r[1] = f2bf(a.y); r[2] = f2bf(a.z); r[3] = f2bf(a.w);
  r[4] = f2bf(b.x); r[5] = f2bf(b.y); r[6] = f2bf(b.z); r[7] = f2bf(b.w);
  *(uint4*)(dst + i) = *(const uint4*)r;
}

// ---------------------------------------------------------------------------
// Projection GEMM: C[8192, 3072] = xb @ [Wq;Wk;Wv]^T  (K=1024, BK=32, 128x128)
//   region 0 -> Qb = (C+bq)*scale   [m][n] bf16
//   region 1 -> Kb = C*scale        [m][n] bf16
//   region 2 -> Vt = C+bv           transposed [b][h][d][s] bf16
// ---------------------------------------------------------------------------
__global__ __launch_bounds__(256) void proj_gemm(
    const u16* __restrict__ xb,
    const u16* __restrict__ Wqb, const u16* __restrict__ Wkb,
    const u16* __restrict__ Wvb,
    const float* __restrict__ bq, const float* __restrict__ bv,
    u16* __restrict__ Qb, u16* __restrict__ Kb, u16* __restrict__ Vt) {
  __shared__ u16 As[128][32];
  __shared__ u16 Bs[128][32];
  const int tid  = threadIdx.x;
  const int lane = tid & 63;
  const int wid  = tid >> 6;
  const int c15  = lane & 15, c4 = lane >> 4;
  const int m0   = blockIdx.x * 128;
  const int nv0  = blockIdx.y * 128;          // virtual col in [0,3072)
  const int region = nv0 >> 10;               // 0=q 1=k 2=v (1024-aligned)
  const int nl0  = nv0 & 1023;
  const u16* Wsrc = (region == 0) ? Wqb : (region == 1) ? Wkb : Wvb;
  const int wrow = wid >> 1, wcol = wid & 1;
  const int srow = lane >> 2, scol = (lane & 3) * 8;

  f32x4 acc[4][4] = {};

  for (int k0 = 0; k0 < 1024; k0 += 32) {
#pragma unroll
    for (int j = 0; j < 2; ++j) {
      const int r = 64 * j + 16 * wid;
      gld_lds16(&As[r][0], xb   + (m0  + r + srow) * 1024 + k0 + scol);
      gld_lds16(&Bs[r][0], Wsrc + (nl0 + r + srow) * 1024 + k0 + scol);
    }
    __syncthreads();
    bf16x8 af[4], bfr[4];
#pragma unroll
    for (int a = 0; a < 4; ++a) af[a]  = ld_bf8(&As[64 * wrow + 16 * a + c15][8 * c4]);
#pragma unroll
    for (int b = 0; b < 4; ++b) bfr[b] = ld_bf8(&Bs[64 * wcol + 16 * b + c15][8 * c4]);
#pragma unroll
    for (int a = 0; a < 4; ++a)
#pragma unroll
      for (int b = 0; b < 4; ++b)
        acc[a][b] = mfma16(af[a], bfr[b], acc[a][b]);
    __syncthreads();
  }

  const float kSc = 0.35355339059327373f;  // 64^-0.25
#pragma unroll
  for (int a = 0; a < 4; ++a) {
    const int mg = m0 + 64 * wrow + 16 * a + 4 * c4;
#pragma unroll
    for (int b = 0; b < 4; ++b) {
      const int nl = 64 * wcol + 16 * b + c15;
      const int nv = nv0 + nl;
      if (region == 0) {
        const float bias = bq[nv];
#pragma unroll
        for (int j = 0; j < 4; ++j)
          Qb[(mg + j) * 1024 + nv] = f2bf((acc[a][b][j] + bias) * kSc);
      } else if (region == 1) {
        const int n = nv - 1024;
#pragma unroll
        for (int j = 0; j < 4; ++j)
          Kb[(mg + j) * 1024 + n] = f2bf(acc[a][b][j] * kSc);
      } else {
        const int n = nv - 2048;             // h*64+d
        const float bias = bv[n];
        const int bb = mg >> 10;             // batch (same for all j: mg%4==0)
        u16* vp = Vt + ((bb * 16 + (n >> 6)) * 64 + (n & 63)) * 1024 + (mg & 1023);
        u16 p[4];
#pragma unroll
        for (int j = 0; j < 4; ++j) p[j] = f2bf(acc[a][b][j] + bias);
        *(uint2*)vp = *(const uint2*)p;      // 4 consecutive s per lane, 8B store
      }
    }
  }
}

// ---------------------------------------------------------------------------
// Attention: one block = (b, h, 32-row q-tile). 4 waves.
//  phase 1: S = Q K^T + mask via 32x32x16 MFMA (128B-coalesced qk stores),
//           write qk (f32), park bf16 S in LDS
//  phase 2: exact softmax from LDS (row max/sum), P back to LDS (unnormalized)
//  phase 3: O = P V / l ; V fragments loaded direct from global Vt (L2-hot)
// ---------------------------------------------------------------------------
__global__ __launch_bounds__(256) void attn_kernel(
    const u16* __restrict__ Qb, const u16* __restrict__ Kb,
    const u16* __restrict__ Vt, const float* __restrict__ mask,
    float* __restrict__ qk, u16* __restrict__ WV) {
  __shared__ u16 S_lds[32][1032];            // 66 KB
  __shared__ float inv_l[32];
  const int tid  = threadIdx.x;
  const int lane = tid & 63;
  const int w    = tid >> 6;
  const int c15  = lane & 15, c4 = lane >> 4;
  const int r31  = lane & 31, hi = lane >> 5;
  const int qt = blockIdx.x, h = blockIdx.y, b = blockIdx.z;
  const int q0  = qt * 32;
  const int bs0 = b * 1024;

  // ---- phase 1: QK^T with 32x32x16; wave w covers s_k in [256w, 256w+256)
  // A-frag: rows q0+r31, k(d) = 16*kk + 8*hi + e
  bf16x8 qf[4];
#pragma unroll
  for (int kk = 0; kk < 4; ++kk)
    qf[kk] = ld_bf8(&Qb[(bs0 + q0 + r31) * 1024 + h * 64 + 16 * kk + 8 * hi]);

  const float* mrow = mask + q0 * 1024;
  float* qkrow = qk + ((b * 16 + h) * 1024 + q0) * 1024;

  for (int c = 0; c < 8; ++c) {
    const int sk0 = 256 * w + 32 * c;
    bf16x8 kf[4];
#pragma unroll
    for (int kk = 0; kk < 4; ++kk)
      kf[kk] = ld_bf8(&Kb[(bs0 + sk0 + r31) * 1024 + h * 64 + 16 * kk + 8 * hi]);
    f32x16 acc = {};
#pragma unroll
    for (int kk = 0; kk < 4; ++kk)
      acc = mfma32(qf[kk], kf[kk], acc);
    const int col = sk0 + r31;
#pragma unroll
    for (int reg = 0; reg < 16; ++reg) {
      const int row = (reg & 3) + 8 * (reg >> 2) + 4 * hi;
      const float v = acc[reg] + mrow[row * 1024 + col];
      qkrow[row * 1024 + col] = v;           // 64 lanes -> 2 x 128B segments
      S_lds[row][col] = f2bf(v);
    }
  }
  __syncthreads();

  // ---- phase 2: softmax (8 threads per row)
  {
    const int row = tid >> 3, sub = tid & 7;
    float m = -1e30f;
#pragma unroll 4
    for (int i = 0; i < 16; ++i) {
      bf16x8 v = ld_bf8(&S_lds[row][(sub + 8 * i) * 8]);
      const u16* vu = (const u16*)&v;
#pragma unroll
      for (int e = 0; e < 8; ++e) m = fmaxf(m, bf2f(vu[e]));
    }
    m = fmaxf(m, __shfl_xor(m, 1, 8));
    m = fmaxf(m, __shfl_xor(m, 2, 8));
    m = fmaxf(m, __shfl_xor(m, 4, 8));
    float s = 0.f;
#pragma unroll 4
    for (int i = 0; i < 16; ++i) {
      bf16x8 v = ld_bf8(&S_lds[row][(sub + 8 * i) * 8]);
      const u16* vu = (const u16*)&v;
      u16 p[8];
#pragma unroll
      for (int e = 0; e < 8; ++e) {
        const float pe = __expf(bf2f(vu[e]) - m);
        s += pe;
        p[e] = f2bf(pe);
      }
      *(uint4*)&S_lds[row][(sub + 8 * i) * 8] = *(const uint4*)p;
    }
    s += __shfl_xor(s, 1, 8);
    s += __shfl_xor(s, 2, 8);
    s += __shfl_xor(s, 4, 8);
    if (sub == 0) inv_l[row] = 1.0f / s;
  }
  __syncthreads();

  // ---- phase 3: PV (16x16); wave w computes output cols d in [16w, 16w+16)
  f32x4 oacc[2] = {};
  const u16* vbase = Vt + ((b * 16 + h) * 64 + 16 * w + c15) * 1024;
  for (int t = 0; t < 32; ++t) {
    bf16x8 pa0 = ld_bf8(&S_lds[c15][32 * t + 8 * c4]);
    bf16x8 pa1 = ld_bf8(&S_lds[16 + c15][32 * t + 8 * c4]);
    bf16x8 vb  = ld_bf8(vbase + 32 * t + 8 * c4);
    oacc[0] = mfma16(pa0, vb, oacc[0]);
    oacc[1] = mfma16(pa1, vb, oacc[1]);
  }
  const int d = 16 * w + c15;
#pragma unroll
  for (int a = 0; a < 2; ++a) {
    const int rl = 16 * a + 4 * c4;
#pragma unroll
    for (int j = 0; j < 4; ++j) {
      const float v = oacc[a][j] * inv_l[rl + j];
      WV[(bs0 + q0 + rl + j) * 1024 + h * 64 + d] = f2bf(v);
    }
  }
}

// ---------------------------------------------------------------------------
// Output GEMM: out[8192,1024] = WV @ Wo^T + bo  (f32 out)
// ---------------------------------------------------------------------------
__global__ __launch_bounds__(256) void out_gemm(
    const u16* __restrict__ Ab, const u16* __restrict__ Wb,
    const float* __restrict__ bias, float* __restrict__ outp) {
  __shared__ u16 As[128][32];
  __shared__ u16 Bs[128][32];
  const int tid  = threadIdx.x;
  const int lane = tid & 63;
  const int wid  = tid >> 6;
  const int c15  = lane & 15, c4 = lane >> 4;
  const int m0   = blockIdx.x * 128;
  const int n0   = blockIdx.y * 128;
  const int wrow = wid >> 1, wcol = wid & 1;
  const int srow = lane >> 2, scol = (lane & 3) * 8;

  f32x4 acc[4][4] = {};

  for (int k0 = 0; k0 < 1024; k0 += 32) {
#pragma unroll
    for (int j = 0; j < 2; ++j) {
      const int r = 64 * j + 16 * wid;
      gld_lds16(&As[r][0], Ab + (m0 + r + srow) * 1024 + k0 + scol);
      gld_lds16(&Bs[r][0], Wb + (n0 + r + srow) * 1024 + k0 + scol);
    }
    __syncthreads();
    bf16x8 af[4], bfr[4];
#pragma unroll
    for (int a = 0; a < 4; ++a) af[a]  = ld_bf8(&As[64 * wrow + 16 * a + c15][8 * c4]);
#pragma unroll
    for (int b = 0; b < 4; ++b) bfr[b] = ld_bf8(&Bs[64 * wcol + 16 * b + c15][8 * c4]);
#pragma unroll
    for (int a = 0; a < 4; ++a)
#pragma unroll
      for (int b = 0; b < 4; ++b)
        acc[a][b] = mfma16(af[a], bfr[b], acc[a][b]);
    __syncthreads();
  }

#pragma unroll
  for (int a = 0; a < 4; ++a) {
    const int mg = m0 + 64 * wrow + 16 * a + 4 * c4;
#pragma unroll
    for (int b = 0; b < 4; ++b) {
      const int ng = n0 + 64 * wcol + 16 * b + c15;
      const float bi = bias[ng];
#pragma unroll
      for (int j = 0; j < 4; ++j)
        outp[(mg + j) * 1024 + ng] = acc[a][b][j] + bi;
    }
  }
}

// ---------------------------------------------------------------------------
extern "C" void kernel_launch(void* const* d_in, const int* in_sizes, int n_in,
                              void* d_out, int out_size, void* d_ws, size_t ws_size,
                              hipStream_t stream) {
  const float* x    = (const float*)d_in[0];
  const float* mask = (const float*)d_in[1];
  const float* Wq   = (const float*)d_in[2];
  const float* bq   = (const float*)d_in[3];
  const float* Wk   = (const float*)d_in[4];
  const float* Wv   = (const float*)d_in[5];
  const float* bv   = (const float*)d_in[6];
  const float* Wo   = (const float*)d_in[7];
  const float* bo   = (const float*)d_in[8];

  float* outp = (float*)d_out;
  float* qk   = outp + 8 * 1024 * 1024;      // second output

  // workspace (bf16 elements): ~88 MB total
  u16* ws  = (u16*)d_ws;
  u16* xb  = ws;                    // 8388608
  u16* Wqb = xb  + 8388608;         // 1048576
  u16* Wkb = Wqb + 1048576;
  u16* Wvb = Wkb + 1048576;
  u16* Wob = Wvb + 1048576;
  u16* Qb  = Wob + 1048576;         // 8388608 (scaled)
  u16* Kb  = Qb  + 8388608;         // 8388608 (scaled)
  u16* Vt  = Kb  + 8388608;         // 8388608 ([b][h][d][s])
  u16* WV  = Vt  + 8388608;         // 8388608

  cvt_f32_bf16<<<4096, 256, 0, stream>>>(x,  xb,  8388608);
  cvt_f32_bf16<<<512,  256, 0, stream>>>(Wq, Wqb, 1048576);
  cvt_f32_bf16<<<512,  256, 0, stream>>>(Wk, Wkb, 1048576);
  cvt_f32_bf16<<<512,  256, 0, stream>>>(Wv, Wvb, 1048576);
  cvt_f32_bf16<<<512,  256, 0, stream>>>(Wo, Wob, 1048576);

  proj_gemm<<<dim3(64, 24), 256, 0, stream>>>(xb, Wqb, Wkb, Wvb, bq, bv, Qb, Kb, Vt);
  attn_kernel<<<dim3(32, 16, 8), 256, 0, stream>>>(Qb, Kb, Vt, mask, qk, WV);
  out_gemm<<<dim3(64, 8), 256, 0, stream>>>(WV, Wob, bo, outp);
}